// Round 13
// baseline (72.476 us; speedup 1.0000x reference)
//
#include <hip/hip_runtime.h>
#include <hip/hip_bf16.h>

// MoE gate (DeepSeek-V2 style): logits = X @ W^T, softmax, group-limited
// top-3-of-8 groups, top-6 experts, normalized weights (sorted desc).
//
// X: [T=32768, H=2048] fp32   W: [64, 2048] fp32   out: [T, 6] fp32
//
// Precision (r9, verified): fp32 = hi+lo FP16 (22 mantissa bits; residual
// split exact; dropped lo*lo ~2^-22). 3 MFMA passes (hh, hl, lh).
//
// Round-13 change vs r12 (67.1us): A-ring 4 -> 8 deep (single variable).
// Ring slots map 1:1 to the 8 steps of a K-256 chunk (static st 0..7),
// prefetch t+8 = next chunk same slot. 16 loads / 16KB in flight per wave
// (128KB/CU, ~2x queue depth) to close the delivery/queuing gap on the
// A-stream (r6 precedent: depth 2->4 = +11%).
// Unchanged from r12: B staged via global_load_lds width=16 into
// wave-uniform + lane*16 slots (no B regs / ds_writes / lgkm stage-drain),
// chunk boundaries use COUNTED s_waitcnt vmcnt(16) (stage proven complete,
// A prefetches never drained), K-256 chunks (8 barriers), LDS 2x64KB.

#define HD 2048
#define NE 64
#define NCH 8        // K-chunks of 256
#define BUFB 65536   // bytes per LDS B buffer: 8 steps * 2 splits * 4KB

typedef __attribute__((ext_vector_type(4))) float f4;
typedef __attribute__((ext_vector_type(8))) short s8;
typedef __attribute__((ext_vector_type(8))) _Float16 h8;
typedef __attribute__((ext_vector_type(4))) float accv;
typedef unsigned short u16;

// fp32 -> hi/lo fp16 split (RNE; residual exact; dropped term ~2^-22).
__device__ __forceinline__ void split8h(const f4 v0, const f4 v1, s8& h, s8& l) {
  #pragma unroll
  for (int i = 0; i < 8; ++i) {
    float a = (i < 4) ? v0[i] : v1[i - 4];
    _Float16 hh = (_Float16)a;
    float r = a - (float)hh;
    _Float16 ll = (_Float16)r;
    h[i] = __builtin_bit_cast(short, hh);
    l[i] = __builtin_bit_cast(short, ll);
  }
}

__device__ __forceinline__ accv mfma3(s8 ah, s8 al, s8 bh, s8 bl, accv t) {
  h8 AH = __builtin_bit_cast(h8, ah);
  h8 AL = __builtin_bit_cast(h8, al);
  h8 BH = __builtin_bit_cast(h8, bh);
  h8 BL = __builtin_bit_cast(h8, bl);
  t = __builtin_amdgcn_mfma_f32_16x16x32_f16(AH, BH, t, 0, 0, 0);
  t = __builtin_amdgcn_mfma_f32_16x16x32_f16(AH, BL, t, 0, 0, 0);
  t = __builtin_amdgcn_mfma_f32_16x16x32_f16(AL, BH, t, 0, 0, 0);
  return t;
}

// Shared epilogue: v[64] logits -> top-3 groups -> top-6 -> normalized weights.
__device__ __forceinline__ void epilogue64(const float* v, float* op) {
  float gm[8];
  #pragma unroll
  for (int g = 0; g < 8; ++g) {
    float mx = v[g * 8];
    #pragma unroll
    for (int j = 1; j < 8; ++j) mx = fmaxf(mx, v[g * 8 + j]);
    gm[g] = mx;
  }
  unsigned selmask = 0u;
  #pragma unroll
  for (int itg = 0; itg < 3; ++itg) {
    float best = gm[0];
    #pragma unroll
    for (int g = 1; g < 8; ++g) best = fmaxf(best, gm[g]);
    int bi = 7;
    #pragma unroll
    for (int g = 6; g >= 0; --g)
      if (gm[g] == best) bi = g;
    selmask |= (1u << bi);
    #pragma unroll
    for (int g = 0; g < 8; ++g) gm[g] = (g == bi) ? -3.0e38f : gm[g];
  }
  float t0 = -3.0e38f, t1 = -3.0e38f, t2 = -3.0e38f;
  float t3 = -3.0e38f, t4 = -3.0e38f, t5 = -3.0e38f;
  #pragma unroll
  for (int g = 0; g < 8; ++g) {
    const bool sel = (selmask >> g) & 1u;
    #pragma unroll
    for (int j = 0; j < 8; ++j) {
      float x = sel ? v[g * 8 + j] : -3.0e38f;
      float mm;
      mm = fmaxf(t0, x); x = fminf(t0, x); t0 = mm;
      mm = fmaxf(t1, x); x = fminf(t1, x); t1 = mm;
      mm = fmaxf(t2, x); x = fminf(t2, x); t2 = mm;
      mm = fmaxf(t3, x); x = fminf(t3, x); t3 = mm;
      mm = fmaxf(t4, x); x = fminf(t4, x); t4 = mm;
      t5 = fmaxf(t5, x);
    }
  }
  float e0 = 1.0f;
  float e1 = __expf(t1 - t0);
  float e2 = __expf(t2 - t0);
  float e3 = __expf(t3 - t0);
  float e4 = __expf(t4 - t0);
  float e5 = __expf(t5 - t0);
  float sum = e0 + e1 + e2 + e3 + e4 + e5;
  float inv = 1.0f / sum;
  op[0] = e0 * inv; op[1] = e1 * inv; op[2] = e2 * inv;
  op[3] = e3 * inv; op[4] = e4 * inv; op[5] = e5 * inv;
}

// ---- kernel 1: split gate weights fp32 -> {hi,lo} fp16 in d_ws ------------
__global__ __launch_bounds__(64) void cvtW2(const float* __restrict__ Wf,
                                            u16* __restrict__ Wh,
                                            u16* __restrict__ Wl) {
  int i = (blockIdx.x * 64 + threadIdx.x) * 8;  // 256 blocks cover 131072
  f4 v0 = *(const f4*)(Wf + i);
  f4 v1 = *(const f4*)(Wf + i + 4);
  s8 h, l;
  split8h(v0, v1, h, l);
  *(s8*)((short*)Wh + i) = h;
  *(s8*)((short*)Wl + i) = l;
}

// ---- kernel 2: fused gate (fp16 2-split, gl_lds staging, 8-deep A-ring) ----
template <bool PRE>
__global__ __launch_bounds__(512, 2) void gateF(
    const float* __restrict__ X, const float* __restrict__ Wf,
    const u16* __restrict__ Wh, const u16* __restrict__ Wl,
    float* __restrict__ out) {
  __shared__ __align__(16) unsigned char smem[2 * BUFB];  // 128 KB

  const int tid = threadIdx.x;
  const int lane = tid & 63;
  const int w = tid >> 6;      // wave 0..7 -> owns tokens tok0 + w*16 ..
  const int ec = lane & 15;    // token row (A) / expert col (B)
  const int kg = lane >> 4;    // 0..3 (8 consecutive k)
  const int tok0 = blockIdx.x * 128;

  // A stream: this wave's 16 token rows
  const float* pA = X + (size_t)(tok0 + w * 16 + ec) * HD + kg * 8;

  // staging role: wave w stages step-in-chunk st=w, all 4 expert groups j,
  // both splits. src: (j*16+ec)*HD + w*32 + kg*8 (+ c*256 per chunk).
  // dst byte: buf + w*8192 + split*4096 + j*1024 + lane*16.
  const size_t wsrcb = (size_t)ec * HD + w * 32 + kg * 8;
  const int sdstb = w * 8192 + lane * 16;

  accv acc[4];
  #pragma unroll
  for (int f = 0; f < 4; ++f) acc[f] = (accv){0.f, 0.f, 0.f, 0.f};

  f4 ar[8][2];  // A raw ring, 8-step lookahead; slot == step-in-chunk

  // --- prologue: stage chunk 0 into buf0; prefetch A steps 0..7 ---
  if constexpr (PRE) {
    #pragma unroll
    for (int j = 0; j < 4; ++j) {
      const size_t o = wsrcb + (size_t)j * 16 * HD;
      __builtin_amdgcn_global_load_lds((const unsigned int*)(Wh + o),
                                       (unsigned int*)(smem + sdstb + j * 1024), 16, 0, 0);
      __builtin_amdgcn_global_load_lds((const unsigned int*)(Wl + o),
                                       (unsigned int*)(smem + sdstb + 4096 + j * 1024), 16, 0, 0);
    }
  } else {
    #pragma unroll
    for (int j = 0; j < 4; ++j) {
      const size_t o = wsrcb + (size_t)j * 16 * HD;
      f4 r0 = *(const f4*)(Wf + o);
      f4 r1 = *(const f4*)(Wf + o + 4);
      s8 th, tl;
      split8h(r0, r1, th, tl);
      *(s8*)(smem + sdstb + j * 1024) = th;
      *(s8*)(smem + sdstb + 4096 + j * 1024) = tl;
    }
  }
  __builtin_amdgcn_sched_barrier(0);
  #pragma unroll
  for (int st = 0; st < 8; ++st) {
    ar[st][0] = *(const f4*)(pA + st * 32);
    ar[st][1] = *(const f4*)(pA + st * 32 + 4);
  }
  __builtin_amdgcn_sched_barrier(0);
  if constexpr (PRE) {
    asm volatile("s_waitcnt vmcnt(16) lgkmcnt(0)");  // 8 stages done; 16 A fly
  } else {
    asm volatile("s_waitcnt lgkmcnt(0)");
  }
  __builtin_amdgcn_s_barrier();
  __builtin_amdgcn_sched_barrier(0);

  // --- main loop: 8 chunks of K=256 (8 MFMA-steps each) ---
  for (int c = 0; c < NCH; ++c) {
    const unsigned char* rb = smem + (c & 1) * BUFB;
    unsigned char* wb = smem + ((c + 1) & 1) * BUFB;
    const bool do_stage = (c + 1 < NCH);

    // issue next-chunk B stage NOW (global_load_lds: lands during compute)
    f4 q0[4], q1[4];  // only used by !PRE fallback
    if (do_stage) {
      if constexpr (PRE) {
        #pragma unroll
        for (int j = 0; j < 4; ++j) {
          const size_t o = wsrcb + (size_t)j * 16 * HD + (size_t)(c + 1) * 256;
          __builtin_amdgcn_global_load_lds((const unsigned int*)(Wh + o),
                                           (unsigned int*)(wb + sdstb + j * 1024), 16, 0, 0);
          __builtin_amdgcn_global_load_lds((const unsigned int*)(Wl + o),
                                           (unsigned int*)(wb + sdstb + 4096 + j * 1024), 16, 0, 0);
        }
      } else {
        #pragma unroll
        for (int j = 0; j < 4; ++j) {
          const size_t o = wsrcb + (size_t)j * 16 * HD + (size_t)(c + 1) * 256;
          q0[j] = *(const f4*)(Wf + o);
          q1[j] = *(const f4*)(Wf + o + 4);
        }
      }
    }
    __builtin_amdgcn_sched_barrier(0);

    #pragma unroll
    for (int st = 0; st < 8; ++st) {
      const int t = c * 8 + st;
      s8 ah, al;
      split8h(ar[st][0], ar[st][1], ah, al);
      const int tn = (t + 8 < 64) ? (t + 8) : 63;  // clamp; dup load harmless
      ar[st][0] = *(const f4*)(pA + tn * 32);
      ar[st][1] = *(const f4*)(pA + tn * 32 + 4);
      #pragma unroll
      for (int f = 0; f < 4; ++f) {
        const unsigned char* bp = rb + st * 8192 + f * 1024 + lane * 16;
        s8 bh = *(const s8*)(bp);
        s8 bl = *(const s8*)(bp + 4096);
        acc[f] = mfma3(ah, al, bh, bl, acc[f]);
      }
    }

    // !PRE fallback: write staged B now (loads have had 8 steps to land)
    if (do_stage) {
      if constexpr (!PRE) {
        #pragma unroll
        for (int j = 0; j < 4; ++j) {
          s8 th, tl;
          split8h(q0[j], q1[j], th, tl);
          *(s8*)(wb + sdstb + j * 1024) = th;
          *(s8*)(wb + sdstb + 4096 + j * 1024) = tl;
        }
      }
    }
    // boundary: counted vmcnt -- the 8 stage ops (oldest in FIFO) proven
    // complete while all 16 A prefetches stay in flight.
    if (do_stage) {
      __builtin_amdgcn_sched_barrier(0);
      if constexpr (PRE) {
        asm volatile("s_waitcnt vmcnt(16) lgkmcnt(0)");
      } else {
        asm volatile("s_waitcnt lgkmcnt(0)");
      }
      __builtin_amdgcn_s_barrier();
      __builtin_amdgcn_sched_barrier(0);
    }
  }

  // --- epilogue: per-wave logit scatter into buf0 region (safe: final chunk
  // reads buf1; all waves are past the chunk-6 barrier) ---
  float* lf = (float*)smem + w * 1088;  // 16 tok x 68 floats
  #pragma unroll
  for (int f = 0; f < 4; ++f)
    #pragma unroll
    for (int r = 0; r < 4; ++r)
      lf[(kg * 4 + r) * 68 + f * 16 + ec] = acc[f][r];

  if (lane < 16) {
    float v[64];
    #pragma unroll
    for (int i = 0; i < 16; ++i) {
      f4 q = *(const f4*)(lf + lane * 68 + 4 * i);
      v[4 * i + 0] = q.x; v[4 * i + 1] = q.y;
      v[4 * i + 2] = q.z; v[4 * i + 3] = q.w;
    }
    epilogue64(v, out + (size_t)(tok0 + w * 16 + lane) * 6);
  }
}

extern "C" void kernel_launch(void* const* d_in, const int* in_sizes, int n_in,
                              void* d_out, int out_size, void* d_ws, size_t ws_size,
                              hipStream_t stream) {
  const float* X = (const float*)d_in[0];
  const float* Wf = (const float*)d_in[1];
  float* out = (float*)d_out;
  const int T = in_sizes[0] / HD;  // 32768
  const int nblk = T / 128;        // 256 blocks of 512 threads (8 waves)

  const size_t need = (size_t)NE * HD * sizeof(u16);  // 256 KB per split
  if (ws_size >= 2 * need) {
    u16* Whi = (u16*)d_ws;
    u16* Wlo = Whi + (size_t)NE * HD;
    cvtW2<<<dim3(256), dim3(64), 0, stream>>>(Wf, Whi, Wlo);
    gateF<true><<<dim3(nblk), dim3(512), 0, stream>>>(X, Wf, Whi, Wlo, out);
  } else {
    gateF<false><<<dim3(nblk), dim3(512), 0, stream>>>(X, Wf, nullptr, nullptr, out);
  }
}

// Round 14
// 70.846 us; speedup vs baseline: 1.0230x; 1.0230x over previous
//
#include <hip/hip_runtime.h>
#include <hip/hip_bf16.h>

// MoE gate (DeepSeek-V2 style): logits = X @ W^T, softmax, group-limited
// top-3-of-8 groups, top-6 experts, normalized weights (sorted desc).
//
// X: [T=32768, H=2048] fp32   W: [64, 2048] fp32   out: [T, 6] fp32
//
// Precision (r9, verified): fp32 = hi+lo FP16 (22 mantissa bits; residual
// split exact; dropped lo*lo ~2^-22). 3 MFMA passes (hh, hl, lh).
//
// Round-14 change vs r12 (67.1us): 4 WAVES/SIMD via 2 blocks/CU (the one
// TLP lever with no extra A-traffic, untried unconfounded). Same 512-thr /
// 8-wave / 16-tok-per-wave full-K block; chunks K-256 -> K-128 so LDS is
// 2x32KB = 64KB/block -> 2 blocks/CU at __launch_bounds__(512,4) (VGPR cap
// 128, tally ~100, no spill). B-stage L2 traffic doubles (~11us aggregate,
// hidden under compute via global_load_lds). Staging: wave w stages step
// w>>1, split w&1 (4 gl_lds/chunk); boundary = counted s_waitcnt vmcnt(8)
// (4 stage ops proven done, 8 A-prefetches stay in flight). Ring 4-deep,
// slot == step-in-chunk. One __syncthreads before the epilogue scatter
// (lf overflows buf0 by 2KB into buf1 which the final chunk reads).

#define HD 2048
#define NE 64
#define NCH 16       // K-chunks of 128
#define BUFB 32768   // bytes per LDS B buffer: 4 steps * 2 splits * 4KB

typedef __attribute__((ext_vector_type(4))) float f4;
typedef __attribute__((ext_vector_type(8))) short s8;
typedef __attribute__((ext_vector_type(8))) _Float16 h8;
typedef __attribute__((ext_vector_type(4))) float accv;
typedef unsigned short u16;

// fp32 -> hi/lo fp16 split (RNE; residual exact; dropped term ~2^-22).
__device__ __forceinline__ void split8h(const f4 v0, const f4 v1, s8& h, s8& l) {
  #pragma unroll
  for (int i = 0; i < 8; ++i) {
    float a = (i < 4) ? v0[i] : v1[i - 4];
    _Float16 hh = (_Float16)a;
    float r = a - (float)hh;
    _Float16 ll = (_Float16)r;
    h[i] = __builtin_bit_cast(short, hh);
    l[i] = __builtin_bit_cast(short, ll);
  }
}

__device__ __forceinline__ accv mfma3(s8 ah, s8 al, s8 bh, s8 bl, accv t) {
  h8 AH = __builtin_bit_cast(h8, ah);
  h8 AL = __builtin_bit_cast(h8, al);
  h8 BH = __builtin_bit_cast(h8, bh);
  h8 BL = __builtin_bit_cast(h8, bl);
  t = __builtin_amdgcn_mfma_f32_16x16x32_f16(AH, BH, t, 0, 0, 0);
  t = __builtin_amdgcn_mfma_f32_16x16x32_f16(AH, BL, t, 0, 0, 0);
  t = __builtin_amdgcn_mfma_f32_16x16x32_f16(AL, BH, t, 0, 0, 0);
  return t;
}

// Shared epilogue: v[64] logits -> top-3 groups -> top-6 -> normalized weights.
__device__ __forceinline__ void epilogue64(const float* v, float* op) {
  float gm[8];
  #pragma unroll
  for (int g = 0; g < 8; ++g) {
    float mx = v[g * 8];
    #pragma unroll
    for (int j = 1; j < 8; ++j) mx = fmaxf(mx, v[g * 8 + j]);
    gm[g] = mx;
  }
  unsigned selmask = 0u;
  #pragma unroll
  for (int itg = 0; itg < 3; ++itg) {
    float best = gm[0];
    #pragma unroll
    for (int g = 1; g < 8; ++g) best = fmaxf(best, gm[g]);
    int bi = 7;
    #pragma unroll
    for (int g = 6; g >= 0; --g)
      if (gm[g] == best) bi = g;
    selmask |= (1u << bi);
    #pragma unroll
    for (int g = 0; g < 8; ++g) gm[g] = (g == bi) ? -3.0e38f : gm[g];
  }
  float t0 = -3.0e38f, t1 = -3.0e38f, t2 = -3.0e38f;
  float t3 = -3.0e38f, t4 = -3.0e38f, t5 = -3.0e38f;
  #pragma unroll
  for (int g = 0; g < 8; ++g) {
    const bool sel = (selmask >> g) & 1u;
    #pragma unroll
    for (int j = 0; j < 8; ++j) {
      float x = sel ? v[g * 8 + j] : -3.0e38f;
      float mm;
      mm = fmaxf(t0, x); x = fminf(t0, x); t0 = mm;
      mm = fmaxf(t1, x); x = fminf(t1, x); t1 = mm;
      mm = fmaxf(t2, x); x = fminf(t2, x); t2 = mm;
      mm = fmaxf(t3, x); x = fminf(t3, x); t3 = mm;
      mm = fmaxf(t4, x); x = fminf(t4, x); t4 = mm;
      t5 = fmaxf(t5, x);
    }
  }
  float e0 = 1.0f;
  float e1 = __expf(t1 - t0);
  float e2 = __expf(t2 - t0);
  float e3 = __expf(t3 - t0);
  float e4 = __expf(t4 - t0);
  float e5 = __expf(t5 - t0);
  float sum = e0 + e1 + e2 + e3 + e4 + e5;
  float inv = 1.0f / sum;
  op[0] = e0 * inv; op[1] = e1 * inv; op[2] = e2 * inv;
  op[3] = e3 * inv; op[4] = e4 * inv; op[5] = e5 * inv;
}

// ---- kernel 1: split gate weights fp32 -> {hi,lo} fp16 in d_ws ------------
__global__ __launch_bounds__(64) void cvtW2(const float* __restrict__ Wf,
                                            u16* __restrict__ Wh,
                                            u16* __restrict__ Wl) {
  int i = (blockIdx.x * 64 + threadIdx.x) * 8;  // 256 blocks cover 131072
  f4 v0 = *(const f4*)(Wf + i);
  f4 v1 = *(const f4*)(Wf + i + 4);
  s8 h, l;
  split8h(v0, v1, h, l);
  *(s8*)((short*)Wh + i) = h;
  *(s8*)((short*)Wl + i) = l;
}

// ---- kernel 2: fused gate (fp16 2-split, gl_lds staging, 2 blocks/CU) ------
template <bool PRE>
__global__ __launch_bounds__(512, 4) void gateF(
    const float* __restrict__ X, const float* __restrict__ Wf,
    const u16* __restrict__ Wh, const u16* __restrict__ Wl,
    float* __restrict__ out) {
  __shared__ __align__(16) unsigned char smem[2 * BUFB];  // 64 KB

  const int tid = threadIdx.x;
  const int lane = tid & 63;
  const int w = tid >> 6;      // wave 0..7 -> owns tokens tok0 + w*16 ..
  const int ec = lane & 15;    // token row (A) / expert col (B)
  const int kg = lane >> 4;    // 0..3 (8 consecutive k)
  const int tok0 = blockIdx.x * 128;

  // A stream: this wave's 16 token rows
  const float* pA = X + (size_t)(tok0 + w * 16 + ec) * HD + kg * 8;

  // staging role: wave w stages step sw = w>>1, split spl = w&1, groups 0..3.
  // src: (j*16+ec)*HD + sw*32 + kg*8 (+ (c+1)*128 per chunk), from Wh or Wl.
  // dst byte: buf + sw*8192 + spl*4096 + j*1024 + lane*16.
  const int sw = w >> 1, spl = w & 1;
  const u16* Wsrc = spl ? Wl : Wh;
  const size_t wsrcb = (size_t)ec * HD + sw * 32 + kg * 8;
  const int sdstb = sw * 8192 + spl * 4096 + lane * 16;

  accv acc[4];
  #pragma unroll
  for (int f = 0; f < 4; ++f) acc[f] = (accv){0.f, 0.f, 0.f, 0.f};

  f4 ar[4][2];  // A raw ring, 4-step lookahead; slot == step-in-chunk

  // --- prologue: stage chunk 0 into buf0; prefetch A steps 0..3 ---
  if constexpr (PRE) {
    #pragma unroll
    for (int j = 0; j < 4; ++j) {
      const size_t o = wsrcb + (size_t)j * 16 * HD;
      __builtin_amdgcn_global_load_lds((const unsigned int*)(Wsrc + o),
                                       (unsigned int*)(smem + sdstb + j * 1024), 16, 0, 0);
    }
  } else {
    #pragma unroll
    for (int j = 0; j < 4; ++j) {
      const size_t o = wsrcb + (size_t)j * 16 * HD;
      f4 r0 = *(const f4*)(Wf + o);
      f4 r1 = *(const f4*)(Wf + o + 4);
      s8 th, tl;
      split8h(r0, r1, th, tl);
      // !PRE: this wave writes BOTH splits of its (sw, j) units; spl unused
      *(s8*)(smem + sw * 8192 + j * 1024 + lane * 16) = th;
      *(s8*)(smem + sw * 8192 + 4096 + j * 1024 + lane * 16) = tl;
    }
  }
  __builtin_amdgcn_sched_barrier(0);
  #pragma unroll
  for (int st = 0; st < 4; ++st) {
    ar[st][0] = *(const f4*)(pA + st * 32);
    ar[st][1] = *(const f4*)(pA + st * 32 + 4);
  }
  __builtin_amdgcn_sched_barrier(0);
  if constexpr (PRE) {
    asm volatile("s_waitcnt vmcnt(8) lgkmcnt(0)");  // 4 stages done; 8 A fly
  } else {
    asm volatile("s_waitcnt lgkmcnt(0)");
  }
  __builtin_amdgcn_s_barrier();
  __builtin_amdgcn_sched_barrier(0);

  // NOTE (!PRE): waves w and w+1 (same sw) both write the same units in the
  // !PRE path; identical data, benign. PRE path partitions by spl.

  // --- main loop: 16 chunks of K=128 (4 MFMA-steps each) ---
  for (int c = 0; c < NCH; ++c) {
    const unsigned char* rb = smem + (c & 1) * BUFB;
    unsigned char* wb = smem + ((c + 1) & 1) * BUFB;
    const bool do_stage = (c + 1 < NCH);

    // issue next-chunk B stage NOW (global_load_lds: lands during compute)
    f4 q0[4], q1[4];  // only used by !PRE fallback
    if (do_stage) {
      if constexpr (PRE) {
        #pragma unroll
        for (int j = 0; j < 4; ++j) {
          const size_t o = wsrcb + (size_t)j * 16 * HD + (size_t)(c + 1) * 128;
          __builtin_amdgcn_global_load_lds((const unsigned int*)(Wsrc + o),
                                           (unsigned int*)(wb + sdstb + j * 1024), 16, 0, 0);
        }
      } else {
        #pragma unroll
        for (int j = 0; j < 4; ++j) {
          const size_t o = wsrcb + (size_t)j * 16 * HD + (size_t)(c + 1) * 128;
          q0[j] = *(const f4*)(Wf + o);
          q1[j] = *(const f4*)(Wf + o + 4);
        }
      }
    }
    __builtin_amdgcn_sched_barrier(0);

    #pragma unroll
    for (int st = 0; st < 4; ++st) {
      const int t = c * 4 + st;
      s8 ah, al;
      split8h(ar[st][0], ar[st][1], ah, al);
      const int tn = (t + 4 < 64) ? (t + 4) : 63;  // clamp; dup load harmless
      ar[st][0] = *(const f4*)(pA + tn * 32);
      ar[st][1] = *(const f4*)(pA + tn * 32 + 4);
      #pragma unroll
      for (int f = 0; f < 4; ++f) {
        const unsigned char* bp = rb + st * 8192 + f * 1024 + lane * 16;
        s8 bh = *(const s8*)(bp);
        s8 bl = *(const s8*)(bp + 4096);
        acc[f] = mfma3(ah, al, bh, bl, acc[f]);
      }
    }

    // !PRE fallback: write staged B now (loads have had 4 steps to land)
    if (do_stage) {
      if constexpr (!PRE) {
        #pragma unroll
        for (int j = 0; j < 4; ++j) {
          s8 th, tl;
          split8h(q0[j], q1[j], th, tl);
          *(s8*)(wb + sw * 8192 + j * 1024 + lane * 16) = th;
          *(s8*)(wb + sw * 8192 + 4096 + j * 1024 + lane * 16) = tl;
        }
      }
    }
    // boundary: counted vmcnt -- the 4 stage ops (oldest in FIFO) proven
    // complete while all 8 A prefetches stay in flight.
    if (do_stage) {
      __builtin_amdgcn_sched_barrier(0);
      if constexpr (PRE) {
        asm volatile("s_waitcnt vmcnt(8) lgkmcnt(0)");
      } else {
        asm volatile("s_waitcnt lgkmcnt(0)");
      }
      __builtin_amdgcn_s_barrier();
      __builtin_amdgcn_sched_barrier(0);
    }
  }

  // --- epilogue: lf spans 34816B > BUFB, overlapping buf1 which the final
  // chunk reads -> barrier first so all waves are done with buf1. ---
  __syncthreads();
  float* lf = (float*)smem + w * 1088;  // 16 tok x 68 floats
  #pragma unroll
  for (int f = 0; f < 4; ++f)
    #pragma unroll
    for (int r = 0; r < 4; ++r)
      lf[(kg * 4 + r) * 68 + f * 16 + ec] = acc[f][r];

  if (lane < 16) {
    float v[64];
    #pragma unroll
    for (int i = 0; i < 16; ++i) {
      f4 q = *(const f4*)(lf + lane * 68 + 4 * i);
      v[4 * i + 0] = q.x; v[4 * i + 1] = q.y;
      v[4 * i + 2] = q.z; v[4 * i + 3] = q.w;
    }
    epilogue64(v, out + (size_t)(tok0 + w * 16 + lane) * 6);
  }
}

extern "C" void kernel_launch(void* const* d_in, const int* in_sizes, int n_in,
                              void* d_out, int out_size, void* d_ws, size_t ws_size,
                              hipStream_t stream) {
  const float* X = (const float*)d_in[0];
  const float* Wf = (const float*)d_in[1];
  float* out = (float*)d_out;
  const int T = in_sizes[0] / HD;  // 32768
  const int nblk = T / 128;        // 256 blocks of 512 threads (8 waves)

  const size_t need = (size_t)NE * HD * sizeof(u16);  // 256 KB per split
  if (ws_size >= 2 * need) {
    u16* Whi = (u16*)d_ws;
    u16* Wlo = Whi + (size_t)NE * HD;
    cvtW2<<<dim3(256), dim3(64), 0, stream>>>(Wf, Whi, Wlo);
    gateF<true><<<dim3(nblk), dim3(512), 0, stream>>>(X, Wf, Whi, Wlo, out);
  } else {
    gateF<false><<<dim3(nblk), dim3(512), 0, stream>>>(X, Wf, nullptr, nullptr, out);
  }
}

// Round 15
// 66.941 us; speedup vs baseline: 1.0827x; 1.0583x over previous
//
#include <hip/hip_runtime.h>
#include <hip/hip_bf16.h>

// MoE gate (DeepSeek-V2 style): logits = X @ W^T, softmax, group-limited
// top-3-of-8 groups, top-6 experts, normalized weights (sorted desc).
//
// X: [T=32768, H=2048] fp32   W: [64, 2048] fp32   out: [T, 6] fp32
//
// Precision (r9, verified): fp32 = hi+lo FP16 (22 mantissa bits; residual
// split exact; dropped lo*lo ~2^-22). 3 MFMA passes (hh, hl, lh).
//
// Round-15: RESTORE r12 verbatim (67.1us, best). The scan around it is
// complete and negative on every axis: ring depth (2- 4+ 8-), chunk K
// (64- 128- 256+), waves/SIMD (2+ 4-), split passes (6- 3+), staging
// (reg+ds_write- gl_lds+), barriers (drain- counted+). r13 (8-ring) and
// r14 (2 blk/CU) both regressed; this banks the optimum.
//  - B staged with global_load_lds width=16 (dst = wave-uniform + lane*16):
//    no B regs, no ds_writes, no lgkm stage-drain.
//  - Chunk boundary: counted s_waitcnt vmcnt(16) -- 8 stage ops (oldest in
//    FIFO) proven complete while all 16 A prefetches stay in flight.
//  - K-256 chunks (8 steps, 8 barriers), LDS 2x64KB; A-ring 4-deep.

#define HD 2048
#define NE 64
#define NCH 8        // K-chunks of 256
#define BUFB 65536   // bytes per LDS B buffer: 8 steps * 2 splits * 4KB

typedef __attribute__((ext_vector_type(4))) float f4;
typedef __attribute__((ext_vector_type(8))) short s8;
typedef __attribute__((ext_vector_type(8))) _Float16 h8;
typedef __attribute__((ext_vector_type(4))) float accv;
typedef unsigned short u16;

// fp32 -> hi/lo fp16 split (RNE; residual exact; dropped term ~2^-22).
__device__ __forceinline__ void split8h(const f4 v0, const f4 v1, s8& h, s8& l) {
  #pragma unroll
  for (int i = 0; i < 8; ++i) {
    float a = (i < 4) ? v0[i] : v1[i - 4];
    _Float16 hh = (_Float16)a;
    float r = a - (float)hh;
    _Float16 ll = (_Float16)r;
    h[i] = __builtin_bit_cast(short, hh);
    l[i] = __builtin_bit_cast(short, ll);
  }
}

__device__ __forceinline__ accv mfma3(s8 ah, s8 al, s8 bh, s8 bl, accv t) {
  h8 AH = __builtin_bit_cast(h8, ah);
  h8 AL = __builtin_bit_cast(h8, al);
  h8 BH = __builtin_bit_cast(h8, bh);
  h8 BL = __builtin_bit_cast(h8, bl);
  t = __builtin_amdgcn_mfma_f32_16x16x32_f16(AH, BH, t, 0, 0, 0);
  t = __builtin_amdgcn_mfma_f32_16x16x32_f16(AH, BL, t, 0, 0, 0);
  t = __builtin_amdgcn_mfma_f32_16x16x32_f16(AL, BH, t, 0, 0, 0);
  return t;
}

// Shared epilogue: v[64] logits -> top-3 groups -> top-6 -> normalized weights.
__device__ __forceinline__ void epilogue64(const float* v, float* op) {
  float gm[8];
  #pragma unroll
  for (int g = 0; g < 8; ++g) {
    float mx = v[g * 8];
    #pragma unroll
    for (int j = 1; j < 8; ++j) mx = fmaxf(mx, v[g * 8 + j]);
    gm[g] = mx;
  }
  unsigned selmask = 0u;
  #pragma unroll
  for (int itg = 0; itg < 3; ++itg) {
    float best = gm[0];
    #pragma unroll
    for (int g = 1; g < 8; ++g) best = fmaxf(best, gm[g]);
    int bi = 7;
    #pragma unroll
    for (int g = 6; g >= 0; --g)
      if (gm[g] == best) bi = g;
    selmask |= (1u << bi);
    #pragma unroll
    for (int g = 0; g < 8; ++g) gm[g] = (g == bi) ? -3.0e38f : gm[g];
  }
  float t0 = -3.0e38f, t1 = -3.0e38f, t2 = -3.0e38f;
  float t3 = -3.0e38f, t4 = -3.0e38f, t5 = -3.0e38f;
  #pragma unroll
  for (int g = 0; g < 8; ++g) {
    const bool sel = (selmask >> g) & 1u;
    #pragma unroll
    for (int j = 0; j < 8; ++j) {
      float x = sel ? v[g * 8 + j] : -3.0e38f;
      float mm;
      mm = fmaxf(t0, x); x = fminf(t0, x); t0 = mm;
      mm = fmaxf(t1, x); x = fminf(t1, x); t1 = mm;
      mm = fmaxf(t2, x); x = fminf(t2, x); t2 = mm;
      mm = fmaxf(t3, x); x = fminf(t3, x); t3 = mm;
      mm = fmaxf(t4, x); x = fminf(t4, x); t4 = mm;
      t5 = fmaxf(t5, x);
    }
  }
  float e0 = 1.0f;
  float e1 = __expf(t1 - t0);
  float e2 = __expf(t2 - t0);
  float e3 = __expf(t3 - t0);
  float e4 = __expf(t4 - t0);
  float e5 = __expf(t5 - t0);
  float sum = e0 + e1 + e2 + e3 + e4 + e5;
  float inv = 1.0f / sum;
  op[0] = e0 * inv; op[1] = e1 * inv; op[2] = e2 * inv;
  op[3] = e3 * inv; op[4] = e4 * inv; op[5] = e5 * inv;
}

// ---- kernel 1: split gate weights fp32 -> {hi,lo} fp16 in d_ws ------------
__global__ __launch_bounds__(64) void cvtW2(const float* __restrict__ Wf,
                                            u16* __restrict__ Wh,
                                            u16* __restrict__ Wl) {
  int i = (blockIdx.x * 64 + threadIdx.x) * 8;  // 256 blocks cover 131072
  f4 v0 = *(const f4*)(Wf + i);
  f4 v1 = *(const f4*)(Wf + i + 4);
  s8 h, l;
  split8h(v0, v1, h, l);
  *(s8*)((short*)Wh + i) = h;
  *(s8*)((short*)Wl + i) = l;
}

// ---- kernel 2: fused gate (fp16 2-split, gl_lds staging, K-256 chunks) -----
template <bool PRE>
__global__ __launch_bounds__(512, 2) void gateF(
    const float* __restrict__ X, const float* __restrict__ Wf,
    const u16* __restrict__ Wh, const u16* __restrict__ Wl,
    float* __restrict__ out) {
  __shared__ __align__(16) unsigned char smem[2 * BUFB];  // 128 KB

  const int tid = threadIdx.x;
  const int lane = tid & 63;
  const int w = tid >> 6;      // wave 0..7 -> owns tokens tok0 + w*16 ..
  const int ec = lane & 15;    // token row (A) / expert col (B)
  const int kg = lane >> 4;    // 0..3 (8 consecutive k)
  const int tok0 = blockIdx.x * 128;

  // A stream: this wave's 16 token rows
  const float* pA = X + (size_t)(tok0 + w * 16 + ec) * HD + kg * 8;

  // staging role: wave w stages step-in-chunk st=w, all 4 expert groups j,
  // both splits. src: (j*16+ec)*HD + w*32 + kg*8 (+ c*256 per chunk).
  // dst byte: buf + w*8192 + split*4096 + j*1024 + lane*16.
  const size_t wsrcb = (size_t)ec * HD + w * 32 + kg * 8;
  const int sdstb = w * 8192 + lane * 16;

  accv acc[4];
  #pragma unroll
  for (int f = 0; f < 4; ++f) acc[f] = (accv){0.f, 0.f, 0.f, 0.f};

  f4 ar[4][2];  // A raw ring, 4-step lookahead (static slots)

  // --- prologue: stage chunk 0 into buf0; prefetch A steps 0..3 ---
  if constexpr (PRE) {
    #pragma unroll
    for (int j = 0; j < 4; ++j) {
      const size_t o = wsrcb + (size_t)j * 16 * HD;
      __builtin_amdgcn_global_load_lds((const unsigned int*)(Wh + o),
                                       (unsigned int*)(smem + sdstb + j * 1024), 16, 0, 0);
      __builtin_amdgcn_global_load_lds((const unsigned int*)(Wl + o),
                                       (unsigned int*)(smem + sdstb + 4096 + j * 1024), 16, 0, 0);
    }
  } else {
    #pragma unroll
    for (int j = 0; j < 4; ++j) {
      const size_t o = wsrcb + (size_t)j * 16 * HD;
      f4 r0 = *(const f4*)(Wf + o);
      f4 r1 = *(const f4*)(Wf + o + 4);
      s8 th, tl;
      split8h(r0, r1, th, tl);
      *(s8*)(smem + sdstb + j * 1024) = th;
      *(s8*)(smem + sdstb + 4096 + j * 1024) = tl;
    }
  }
  __builtin_amdgcn_sched_barrier(0);
  #pragma unroll
  for (int st = 0; st < 4; ++st) {
    ar[st][0] = *(const f4*)(pA + st * 32);
    ar[st][1] = *(const f4*)(pA + st * 32 + 4);
  }
  __builtin_amdgcn_sched_barrier(0);
  if constexpr (PRE) {
    asm volatile("s_waitcnt vmcnt(8) lgkmcnt(0)");  // stage done; 8 A-loads fly
  } else {
    asm volatile("s_waitcnt lgkmcnt(0)");
  }
  __builtin_amdgcn_s_barrier();
  __builtin_amdgcn_sched_barrier(0);

  // --- main loop: 8 chunks of K=256 (8 MFMA-steps each) ---
  for (int c = 0; c < NCH; ++c) {
    const unsigned char* rb = smem + (c & 1) * BUFB;
    unsigned char* wb = smem + ((c + 1) & 1) * BUFB;
    const bool do_stage = (c + 1 < NCH);

    // issue next-chunk B stage NOW (global_load_lds: lands during compute)
    f4 q0[4], q1[4];  // only used by !PRE fallback
    if (do_stage) {
      if constexpr (PRE) {
        #pragma unroll
        for (int j = 0; j < 4; ++j) {
          const size_t o = wsrcb + (size_t)j * 16 * HD + (size_t)(c + 1) * 256;
          __builtin_amdgcn_global_load_lds((const unsigned int*)(Wh + o),
                                           (unsigned int*)(wb + sdstb + j * 1024), 16, 0, 0);
          __builtin_amdgcn_global_load_lds((const unsigned int*)(Wl + o),
                                           (unsigned int*)(wb + sdstb + 4096 + j * 1024), 16, 0, 0);
        }
      } else {
        #pragma unroll
        for (int j = 0; j < 4; ++j) {
          const size_t o = wsrcb + (size_t)j * 16 * HD + (size_t)(c + 1) * 256;
          q0[j] = *(const f4*)(Wf + o);
          q1[j] = *(const f4*)(Wf + o + 4);
        }
      }
    }
    __builtin_amdgcn_sched_barrier(0);

    #pragma unroll
    for (int st = 0; st < 8; ++st) {
      const int t = c * 8 + st;
      s8 ah, al;
      split8h(ar[st & 3][0], ar[st & 3][1], ah, al);
      const int tn = (t + 4 < 64) ? (t + 4) : 63;  // clamp; dup load harmless
      ar[st & 3][0] = *(const f4*)(pA + tn * 32);
      ar[st & 3][1] = *(const f4*)(pA + tn * 32 + 4);
      #pragma unroll
      for (int f = 0; f < 4; ++f) {
        const unsigned char* bp = rb + st * 8192 + f * 1024 + lane * 16;
        s8 bh = *(const s8*)(bp);
        s8 bl = *(const s8*)(bp + 4096);
        acc[f] = mfma3(ah, al, bh, bl, acc[f]);
      }
    }

    // !PRE fallback: write staged B now (loads have had 8 steps to land)
    if (do_stage) {
      if constexpr (!PRE) {
        #pragma unroll
        for (int j = 0; j < 4; ++j) {
          s8 th, tl;
          split8h(q0[j], q1[j], th, tl);
          *(s8*)(wb + sdstb + j * 1024) = th;
          *(s8*)(wb + sdstb + 4096 + j * 1024) = tl;
        }
      }
    }
    // boundary: counted vmcnt -- stage(c+1) proven complete (8 stage instrs
    // oldest in FIFO); A prefetches stay in flight.
    if (do_stage) {
      __builtin_amdgcn_sched_barrier(0);
      if constexpr (PRE) {
        asm volatile("s_waitcnt vmcnt(16) lgkmcnt(0)");
      } else {
        asm volatile("s_waitcnt lgkmcnt(0)");
      }
      __builtin_amdgcn_s_barrier();
      __builtin_amdgcn_sched_barrier(0);
    }
  }

  // --- epilogue: per-wave logit scatter into buf0 region (safe: final chunk
  // reads buf1; all waves are past the chunk-6 barrier) ---
  float* lf = (float*)smem + w * 1088;  // 16 tok x 68 floats
  #pragma unroll
  for (int f = 0; f < 4; ++f)
    #pragma unroll
    for (int r = 0; r < 4; ++r)
      lf[(kg * 4 + r) * 68 + f * 16 + ec] = acc[f][r];

  if (lane < 16) {
    float v[64];
    #pragma unroll
    for (int i = 0; i < 16; ++i) {
      f4 q = *(const f4*)(lf + lane * 68 + 4 * i);
      v[4 * i + 0] = q.x; v[4 * i + 1] = q.y;
      v[4 * i + 2] = q.z; v[4 * i + 3] = q.w;
    }
    epilogue64(v, out + (size_t)(tok0 + w * 16 + lane) * 6);
  }
}

extern "C" void kernel_launch(void* const* d_in, const int* in_sizes, int n_in,
                              void* d_out, int out_size, void* d_ws, size_t ws_size,
                              hipStream_t stream) {
  const float* X = (const float*)d_in[0];
  const float* Wf = (const float*)d_in[1];
  float* out = (float*)d_out;
  const int T = in_sizes[0] / HD;  // 32768
  const int nblk = T / 128;        // 256 blocks of 512 threads (8 waves)

  const size_t need = (size_t)NE * HD * sizeof(u16);  // 256 KB per split
  if (ws_size >= 2 * need) {
    u16* Whi = (u16*)d_ws;
    u16* Wlo = Whi + (size_t)NE * HD;
    cvtW2<<<dim3(256), dim3(64), 0, stream>>>(Wf, Whi, Wlo);
    gateF<true><<<dim3(nblk), dim3(512), 0, stream>>>(X, Wf, Whi, Wlo, out);
  } else {
    gateF<false><<<dim3(nblk), dim3(512), 0, stream>>>(X, Wf, nullptr, nullptr, out);
  }
}

// Round 16
// 62.284 us; speedup vs baseline: 1.1636x; 1.0748x over previous
//
#include <hip/hip_runtime.h>
#include <hip/hip_bf16.h>

// MoE gate (DeepSeek-V2 style): logits = X @ W^T, softmax, group-limited
// top-3-of-8 groups, top-6 experts, normalized weights (sorted desc).
//
// X: [T=32768, H=2048] fp32   W: [64, 2048] fp32   out: [T, 6] fp32
//
// Precision (r9, verified): fp32 = hi+lo FP16 (22 mantissa bits; residual
// split exact; dropped lo*lo ~2^-22). 3 MFMA passes (hh, hl, lh).
//
// Round-16: r12/r15 optimum (66.9us) + T5 s_setprio around each step's
// consume cluster (split+MFMA). Catalog: setprio is null on lockstep
// schedules but +21-25% on counted-vmcnt role-diverse schedules (m218b);
// r12's stage-then-compute chunks with vmcnt(16) boundaries are that shape.
// Single-variable change; everything else byte-identical to r15.

#define HD 2048
#define NE 64
#define NCH 8        // K-chunks of 256
#define BUFB 65536   // bytes per LDS B buffer: 8 steps * 2 splits * 4KB

typedef __attribute__((ext_vector_type(4))) float f4;
typedef __attribute__((ext_vector_type(8))) short s8;
typedef __attribute__((ext_vector_type(8))) _Float16 h8;
typedef __attribute__((ext_vector_type(4))) float accv;
typedef unsigned short u16;

// fp32 -> hi/lo fp16 split (RNE; residual exact; dropped term ~2^-22).
__device__ __forceinline__ void split8h(const f4 v0, const f4 v1, s8& h, s8& l) {
  #pragma unroll
  for (int i = 0; i < 8; ++i) {
    float a = (i < 4) ? v0[i] : v1[i - 4];
    _Float16 hh = (_Float16)a;
    float r = a - (float)hh;
    _Float16 ll = (_Float16)r;
    h[i] = __builtin_bit_cast(short, hh);
    l[i] = __builtin_bit_cast(short, ll);
  }
}

__device__ __forceinline__ accv mfma3(s8 ah, s8 al, s8 bh, s8 bl, accv t) {
  h8 AH = __builtin_bit_cast(h8, ah);
  h8 AL = __builtin_bit_cast(h8, al);
  h8 BH = __builtin_bit_cast(h8, bh);
  h8 BL = __builtin_bit_cast(h8, bl);
  t = __builtin_amdgcn_mfma_f32_16x16x32_f16(AH, BH, t, 0, 0, 0);
  t = __builtin_amdgcn_mfma_f32_16x16x32_f16(AH, BL, t, 0, 0, 0);
  t = __builtin_amdgcn_mfma_f32_16x16x32_f16(AL, BH, t, 0, 0, 0);
  return t;
}

// Shared epilogue: v[64] logits -> top-3 groups -> top-6 -> normalized weights.
__device__ __forceinline__ void epilogue64(const float* v, float* op) {
  float gm[8];
  #pragma unroll
  for (int g = 0; g < 8; ++g) {
    float mx = v[g * 8];
    #pragma unroll
    for (int j = 1; j < 8; ++j) mx = fmaxf(mx, v[g * 8 + j]);
    gm[g] = mx;
  }
  unsigned selmask = 0u;
  #pragma unroll
  for (int itg = 0; itg < 3; ++itg) {
    float best = gm[0];
    #pragma unroll
    for (int g = 1; g < 8; ++g) best = fmaxf(best, gm[g]);
    int bi = 7;
    #pragma unroll
    for (int g = 6; g >= 0; --g)
      if (gm[g] == best) bi = g;
    selmask |= (1u << bi);
    #pragma unroll
    for (int g = 0; g < 8; ++g) gm[g] = (g == bi) ? -3.0e38f : gm[g];
  }
  float t0 = -3.0e38f, t1 = -3.0e38f, t2 = -3.0e38f;
  float t3 = -3.0e38f, t4 = -3.0e38f, t5 = -3.0e38f;
  #pragma unroll
  for (int g = 0; g < 8; ++g) {
    const bool sel = (selmask >> g) & 1u;
    #pragma unroll
    for (int j = 0; j < 8; ++j) {
      float x = sel ? v[g * 8 + j] : -3.0e38f;
      float mm;
      mm = fmaxf(t0, x); x = fminf(t0, x); t0 = mm;
      mm = fmaxf(t1, x); x = fminf(t1, x); t1 = mm;
      mm = fmaxf(t2, x); x = fminf(t2, x); t2 = mm;
      mm = fmaxf(t3, x); x = fminf(t3, x); t3 = mm;
      mm = fmaxf(t4, x); x = fminf(t4, x); t4 = mm;
      t5 = fmaxf(t5, x);
    }
  }
  float e0 = 1.0f;
  float e1 = __expf(t1 - t0);
  float e2 = __expf(t2 - t0);
  float e3 = __expf(t3 - t0);
  float e4 = __expf(t4 - t0);
  float e5 = __expf(t5 - t0);
  float sum = e0 + e1 + e2 + e3 + e4 + e5;
  float inv = 1.0f / sum;
  op[0] = e0 * inv; op[1] = e1 * inv; op[2] = e2 * inv;
  op[3] = e3 * inv; op[4] = e4 * inv; op[5] = e5 * inv;
}

// ---- kernel 1: split gate weights fp32 -> {hi,lo} fp16 in d_ws ------------
__global__ __launch_bounds__(64) void cvtW2(const float* __restrict__ Wf,
                                            u16* __restrict__ Wh,
                                            u16* __restrict__ Wl) {
  int i = (blockIdx.x * 64 + threadIdx.x) * 8;  // 256 blocks cover 131072
  f4 v0 = *(const f4*)(Wf + i);
  f4 v1 = *(const f4*)(Wf + i + 4);
  s8 h, l;
  split8h(v0, v1, h, l);
  *(s8*)((short*)Wh + i) = h;
  *(s8*)((short*)Wl + i) = l;
}

// ---- kernel 2: fused gate (fp16 2-split, gl_lds staging, K-256, setprio) ---
template <bool PRE>
__global__ __launch_bounds__(512, 2) void gateF(
    const float* __restrict__ X, const float* __restrict__ Wf,
    const u16* __restrict__ Wh, const u16* __restrict__ Wl,
    float* __restrict__ out) {
  __shared__ __align__(16) unsigned char smem[2 * BUFB];  // 128 KB

  const int tid = threadIdx.x;
  const int lane = tid & 63;
  const int w = tid >> 6;      // wave 0..7 -> owns tokens tok0 + w*16 ..
  const int ec = lane & 15;    // token row (A) / expert col (B)
  const int kg = lane >> 4;    // 0..3 (8 consecutive k)
  const int tok0 = blockIdx.x * 128;

  // A stream: this wave's 16 token rows
  const float* pA = X + (size_t)(tok0 + w * 16 + ec) * HD + kg * 8;

  // staging role: wave w stages step-in-chunk st=w, all 4 expert groups j,
  // both splits. src: (j*16+ec)*HD + w*32 + kg*8 (+ c*256 per chunk).
  // dst byte: buf + w*8192 + split*4096 + j*1024 + lane*16.
  const size_t wsrcb = (size_t)ec * HD + w * 32 + kg * 8;
  const int sdstb = w * 8192 + lane * 16;

  accv acc[4];
  #pragma unroll
  for (int f = 0; f < 4; ++f) acc[f] = (accv){0.f, 0.f, 0.f, 0.f};

  f4 ar[4][2];  // A raw ring, 4-step lookahead (static slots)

  // --- prologue: stage chunk 0 into buf0; prefetch A steps 0..3 ---
  if constexpr (PRE) {
    #pragma unroll
    for (int j = 0; j < 4; ++j) {
      const size_t o = wsrcb + (size_t)j * 16 * HD;
      __builtin_amdgcn_global_load_lds((const unsigned int*)(Wh + o),
                                       (unsigned int*)(smem + sdstb + j * 1024), 16, 0, 0);
      __builtin_amdgcn_global_load_lds((const unsigned int*)(Wl + o),
                                       (unsigned int*)(smem + sdstb + 4096 + j * 1024), 16, 0, 0);
    }
  } else {
    #pragma unroll
    for (int j = 0; j < 4; ++j) {
      const size_t o = wsrcb + (size_t)j * 16 * HD;
      f4 r0 = *(const f4*)(Wf + o);
      f4 r1 = *(const f4*)(Wf + o + 4);
      s8 th, tl;
      split8h(r0, r1, th, tl);
      *(s8*)(smem + sdstb + j * 1024) = th;
      *(s8*)(smem + sdstb + 4096 + j * 1024) = tl;
    }
  }
  __builtin_amdgcn_sched_barrier(0);
  #pragma unroll
  for (int st = 0; st < 4; ++st) {
    ar[st][0] = *(const f4*)(pA + st * 32);
    ar[st][1] = *(const f4*)(pA + st * 32 + 4);
  }
  __builtin_amdgcn_sched_barrier(0);
  if constexpr (PRE) {
    asm volatile("s_waitcnt vmcnt(8) lgkmcnt(0)");  // stage done; 8 A-loads fly
  } else {
    asm volatile("s_waitcnt lgkmcnt(0)");
  }
  __builtin_amdgcn_s_barrier();
  __builtin_amdgcn_sched_barrier(0);

  // --- main loop: 8 chunks of K=256 (8 MFMA-steps each) ---
  for (int c = 0; c < NCH; ++c) {
    const unsigned char* rb = smem + (c & 1) * BUFB;
    unsigned char* wb = smem + ((c + 1) & 1) * BUFB;
    const bool do_stage = (c + 1 < NCH);

    // issue next-chunk B stage NOW (global_load_lds: lands during compute)
    f4 q0[4], q1[4];  // only used by !PRE fallback
    if (do_stage) {
      if constexpr (PRE) {
        #pragma unroll
        for (int j = 0; j < 4; ++j) {
          const size_t o = wsrcb + (size_t)j * 16 * HD + (size_t)(c + 1) * 256;
          __builtin_amdgcn_global_load_lds((const unsigned int*)(Wh + o),
                                           (unsigned int*)(wb + sdstb + j * 1024), 16, 0, 0);
          __builtin_amdgcn_global_load_lds((const unsigned int*)(Wl + o),
                                           (unsigned int*)(wb + sdstb + 4096 + j * 1024), 16, 0, 0);
        }
      } else {
        #pragma unroll
        for (int j = 0; j < 4; ++j) {
          const size_t o = wsrcb + (size_t)j * 16 * HD + (size_t)(c + 1) * 256;
          q0[j] = *(const f4*)(Wf + o);
          q1[j] = *(const f4*)(Wf + o + 4);
        }
      }
    }
    __builtin_amdgcn_sched_barrier(0);

    #pragma unroll
    for (int st = 0; st < 8; ++st) {
      const int t = c * 8 + st;
      // issue A prefetch first (memory role), then raise priority for the
      // consume cluster (split + MFMA) -- T5: scheduler prefers the wave
      // that is feeding the matrix/VALU pipes over co-resident load-issuers.
      const int tn = (t + 4 < 64) ? (t + 4) : 63;  // clamp; dup load harmless
      f4 na0 = *(const f4*)(pA + tn * 32);
      f4 na1 = *(const f4*)(pA + tn * 32 + 4);
      __builtin_amdgcn_s_setprio(1);
      s8 ah, al;
      split8h(ar[st & 3][0], ar[st & 3][1], ah, al);
      #pragma unroll
      for (int f = 0; f < 4; ++f) {
        const unsigned char* bp = rb + st * 8192 + f * 1024 + lane * 16;
        s8 bh = *(const s8*)(bp);
        s8 bl = *(const s8*)(bp + 4096);
        acc[f] = mfma3(ah, al, bh, bl, acc[f]);
      }
      __builtin_amdgcn_s_setprio(0);
      ar[st & 3][0] = na0;
      ar[st & 3][1] = na1;
    }

    // !PRE fallback: write staged B now (loads have had 8 steps to land)
    if (do_stage) {
      if constexpr (!PRE) {
        #pragma unroll
        for (int j = 0; j < 4; ++j) {
          s8 th, tl;
          split8h(q0[j], q1[j], th, tl);
          *(s8*)(wb + sdstb + j * 1024) = th;
          *(s8*)(wb + sdstb + 4096 + j * 1024) = tl;
        }
      }
    }
    // boundary: counted vmcnt -- stage(c+1) proven complete (8 stage instrs
    // oldest in FIFO); A prefetches stay in flight.
    if (do_stage) {
      __builtin_amdgcn_sched_barrier(0);
      if constexpr (PRE) {
        asm volatile("s_waitcnt vmcnt(16) lgkmcnt(0)");
      } else {
        asm volatile("s_waitcnt lgkmcnt(0)");
      }
      __builtin_amdgcn_s_barrier();
      __builtin_amdgcn_sched_barrier(0);
    }
  }

  // --- epilogue: per-wave logit scatter into buf0 region (safe: final chunk
  // reads buf1; all waves are past the chunk-6 barrier) ---
  float* lf = (float*)smem + w * 1088;  // 16 tok x 68 floats
  #pragma unroll
  for (int f = 0; f < 4; ++f)
    #pragma unroll
    for (int r = 0; r < 4; ++r)
      lf[(kg * 4 + r) * 68 + f * 16 + ec] = acc[f][r];

  if (lane < 16) {
    float v[64];
    #pragma unroll
    for (int i = 0; i < 16; ++i) {
      f4 q = *(const f4*)(lf + lane * 68 + 4 * i);
      v[4 * i + 0] = q.x; v[4 * i + 1] = q.y;
      v[4 * i + 2] = q.z; v[4 * i + 3] = q.w;
    }
    epilogue64(v, out + (size_t)(tok0 + w * 16 + lane) * 6);
  }
}

extern "C" void kernel_launch(void* const* d_in, const int* in_sizes, int n_in,
                              void* d_out, int out_size, void* d_ws, size_t ws_size,
                              hipStream_t stream) {
  const float* X = (const float*)d_in[0];
  const float* Wf = (const float*)d_in[1];
  float* out = (float*)d_out;
  const int T = in_sizes[0] / HD;  // 32768
  const int nblk = T / 128;        // 256 blocks of 512 threads (8 waves)

  const size_t need = (size_t)NE * HD * sizeof(u16);  // 256 KB per split
  if (ws_size >= 2 * need) {
    u16* Whi = (u16*)d_ws;
    u16* Wlo = Whi + (size_t)NE * HD;
    cvtW2<<<dim3(256), dim3(64), 0, stream>>>(Wf, Whi, Wlo);
    gateF<true><<<dim3(nblk), dim3(512), 0, stream>>>(X, Wf, Whi, Wlo, out);
  } else {
    gateF<false><<<dim3(nblk), dim3(512), 0, stream>>>(X, Wf, nullptr, nullptr, out);
  }
}

// Round 18
// 57.081 us; speedup vs baseline: 1.2697x; 1.0912x over previous
//
#include <hip/hip_runtime.h>
#include <hip/hip_bf16.h>

// MoE gate (DeepSeek-V2 style): logits = X @ W^T, softmax, group-limited
// top-3-of-8 groups, top-6 experts, normalized weights (sorted desc).
//
// X: [T=32768, H=2048] fp32   W: [64, 2048] fp32   out: [T, 6] fp32
//
// Precision (r9): fp32 = hi+lo FP16, 3 MFMA passes (hh, hl, lh).
//
// Round-18 = round-17 (A through LDS, pre-swizzled gl_lds source) with the
// vmcnt LEDGER FIXED. r17's race: at st4=3 the needed A-pair (staged at
// st4=0 of the SAME chunk) sits behind the chunk-top B ops in the FIFO;
// outstanding = B(4)+3A(6)=10, so vmcnt(8) retired only 2 B ops and never
// proved the A-pair -> stale reads, absmax 0.816. Corrected per-step waits:
//   non-last chunks: {8, 8, 8, 4}   (st4=3's vmcnt(4) retires B(4)+A(2);
//                                    boundary vmcnt(8) becomes a proven no-op)
//   last chunk     : {4, 4, 4, 4}   (no B-top; outstanding = 6)
// FIFO replay (steady chunk): enter out=6(A3); +B(4)=10; s0: w8 retire A,
// issue A ->10; s1,s2 same; s3: w4 retire B+A ->4, issue A ->6; boundary ok.
// Everything else byte-identical to r17 (setprio, swizzle, layouts).

#define HD 2048
#define NE 64
#define NCH 16        // K-chunks of 128 (4 MFMA-steps each)
#define ABASE 0       // A rings: 8 waves * 4 slots * 2KB = 64 KB
#define BBASE 65536   // B double buffer: 2 * 32 KB
#define BBUF 32768

typedef __attribute__((ext_vector_type(4))) float f4;
typedef __attribute__((ext_vector_type(8))) short s8;
typedef __attribute__((ext_vector_type(8))) _Float16 h8;
typedef __attribute__((ext_vector_type(4))) float accv;
typedef unsigned short u16;

// fp32 -> hi/lo fp16 split (RNE; residual exact; dropped term ~2^-22).
__device__ __forceinline__ void split8h(const f4 v0, const f4 v1, s8& h, s8& l) {
  #pragma unroll
  for (int i = 0; i < 8; ++i) {
    float a = (i < 4) ? v0[i] : v1[i - 4];
    _Float16 hh = (_Float16)a;
    float r = a - (float)hh;
    _Float16 ll = (_Float16)r;
    h[i] = __builtin_bit_cast(short, hh);
    l[i] = __builtin_bit_cast(short, ll);
  }
}

__device__ __forceinline__ accv mfma3(s8 ah, s8 al, s8 bh, s8 bl, accv t) {
  h8 AH = __builtin_bit_cast(h8, ah);
  h8 AL = __builtin_bit_cast(h8, al);
  h8 BH = __builtin_bit_cast(h8, bh);
  h8 BL = __builtin_bit_cast(h8, bl);
  t = __builtin_amdgcn_mfma_f32_16x16x32_f16(AH, BH, t, 0, 0, 0);
  t = __builtin_amdgcn_mfma_f32_16x16x32_f16(AH, BL, t, 0, 0, 0);
  t = __builtin_amdgcn_mfma_f32_16x16x32_f16(AL, BH, t, 0, 0, 0);
  return t;
}

// Shared epilogue: v[64] logits -> top-3 groups -> top-6 -> normalized weights.
__device__ __forceinline__ void epilogue64(const float* v, float* op) {
  float gm[8];
  #pragma unroll
  for (int g = 0; g < 8; ++g) {
    float mx = v[g * 8];
    #pragma unroll
    for (int j = 1; j < 8; ++j) mx = fmaxf(mx, v[g * 8 + j]);
    gm[g] = mx;
  }
  unsigned selmask = 0u;
  #pragma unroll
  for (int itg = 0; itg < 3; ++itg) {
    float best = gm[0];
    #pragma unroll
    for (int g = 1; g < 8; ++g) best = fmaxf(best, gm[g]);
    int bi = 7;
    #pragma unroll
    for (int g = 6; g >= 0; --g)
      if (gm[g] == best) bi = g;
    selmask |= (1u << bi);
    #pragma unroll
    for (int g = 0; g < 8; ++g) gm[g] = (g == bi) ? -3.0e38f : gm[g];
  }
  float t0 = -3.0e38f, t1 = -3.0e38f, t2 = -3.0e38f;
  float t3 = -3.0e38f, t4 = -3.0e38f, t5 = -3.0e38f;
  #pragma unroll
  for (int g = 0; g < 8; ++g) {
    const bool sel = (selmask >> g) & 1u;
    #pragma unroll
    for (int j = 0; j < 8; ++j) {
      float x = sel ? v[g * 8 + j] : -3.0e38f;
      float mm;
      mm = fmaxf(t0, x); x = fminf(t0, x); t0 = mm;
      mm = fmaxf(t1, x); x = fminf(t1, x); t1 = mm;
      mm = fmaxf(t2, x); x = fminf(t2, x); t2 = mm;
      mm = fmaxf(t3, x); x = fminf(t3, x); t3 = mm;
      mm = fmaxf(t4, x); x = fminf(t4, x); t4 = mm;
      t5 = fmaxf(t5, x);
    }
  }
  float e0 = 1.0f;
  float e1 = __expf(t1 - t0);
  float e2 = __expf(t2 - t0);
  float e3 = __expf(t3 - t0);
  float e4 = __expf(t4 - t0);
  float e5 = __expf(t5 - t0);
  float sum = e0 + e1 + e2 + e3 + e4 + e5;
  float inv = 1.0f / sum;
  op[0] = e0 * inv; op[1] = e1 * inv; op[2] = e2 * inv;
  op[3] = e3 * inv; op[4] = e4 * inv; op[5] = e5 * inv;
}

// ---- kernel 1: split gate weights fp32 -> {hi,lo} fp16 in d_ws ------------
__global__ __launch_bounds__(64) void cvtW2(const float* __restrict__ Wf,
                                            u16* __restrict__ Wh,
                                            u16* __restrict__ Wl) {
  int i = (blockIdx.x * 64 + threadIdx.x) * 8;  // 256 blocks cover 131072
  f4 v0 = *(const f4*)(Wf + i);
  f4 v1 = *(const f4*)(Wf + i + 4);
  s8 h, l;
  split8h(v0, v1, h, l);
  *(s8*)((short*)Wh + i) = h;
  *(s8*)((short*)Wl + i) = l;
}

// ---- kernel 2: fused gate (A through LDS, swizzled; all-gl_lds VMEM) -------
template <bool PRE>
__global__ __launch_bounds__(512, 2) void gateF(
    const float* __restrict__ X, const float* __restrict__ Wf,
    const u16* __restrict__ Wh, const u16* __restrict__ Wl,
    float* __restrict__ out) {
  __shared__ __align__(16) unsigned char smem[BBASE + 2 * BBUF];  // 128 KB

  const int tid = threadIdx.x;
  const int lane = tid & 63;
  const int w = tid >> 6;      // wave 0..7 -> owns tokens tok0 + w*16 ..
  const int ec = lane & 15;    // token row (A frag) / expert col (B frag)
  const int kg = lane >> 4;    // 0..3 (8 consecutive k)
  const int tok0 = blockIdx.x * 128;

  // --- A staging: per-lane PRE-SWIZZLED global source (T2 both-sides) ---
  // lane l: row=(l>>3), col_float = ((l&7)*4) ^ ((l>>3)<<2); granule (r,g)
  // lands at LDS byte r*128 + ((g^r)<<4) within the 1KB half-slot.
  const int rowlo = lane >> 3;
  const int colf = ((lane & 7) * 4) ^ (rowlo << 2);
  const float* srcA0 = X + (size_t)(tok0 + w * 16 + rowlo) * HD + colf;
  const float* srcA1 = X + (size_t)(tok0 + w * 16 + 8 + rowlo) * HD + colf;
  unsigned char* const aring = smem + ABASE + w * 8192;  // 4 slots x 2KB

  // --- A fragment read: swizzled address (matching involution) ---
  const int a0b = ec * 128 + kg * 32;
  const int sw = (ec & 7) << 4;
  const int rdA0 = a0b ^ sw;
  const int rdA1 = (a0b + 16) ^ sw;

  // --- B staging role (PRE): wave w stages (st=w>>1, split=w&1, j=0..3) ---
  const int bst = w >> 1, bspl = w & 1;
  const u16* WsrcB = bspl ? Wl : Wh;
  const size_t wsrcb = (size_t)ec * HD + bst * 32 + kg * 8;
  const int bdst = bst * 8192 + bspl * 4096 + lane * 16;

  accv acc[4];
  #pragma unroll
  for (int f = 0; f < 4; ++f) acc[f] = (accv){0.f, 0.f, 0.f, 0.f};

  // --- prologue: stage B(c0); A slots 0..2 (prefetch-3) ---
  if constexpr (PRE) {
    #pragma unroll
    for (int j = 0; j < 4; ++j)
      __builtin_amdgcn_global_load_lds(
          (const unsigned int*)(WsrcB + wsrcb + (size_t)j * 16 * HD),
          (unsigned int*)(smem + BBASE + bdst + j * 1024), 16, 0, 0);
  } else {
    #pragma unroll
    for (int j = 0; j < 4; ++j) {
      const size_t o = wsrcb + (size_t)j * 16 * HD;
      f4 r0 = *(const f4*)(Wf + o);
      f4 r1 = *(const f4*)(Wf + o + 4);
      s8 th, tl;
      split8h(r0, r1, th, tl);
      *(s8*)(smem + BBASE + bst * 8192 + bspl * 4096 + j * 1024 + lane * 16) =
          bspl ? tl : th;
    }
  }
  #pragma unroll
  for (int st = 0; st < 3; ++st) {
    unsigned char* ad = aring + st * 2048 + lane * 16;
    __builtin_amdgcn_global_load_lds((const unsigned int*)(srcA0 + st * 32),
                                     (unsigned int*)(ad), 16, 0, 0);
    __builtin_amdgcn_global_load_lds((const unsigned int*)(srcA1 + st * 32),
                                     (unsigned int*)(ad + 1024), 16, 0, 0);
  }
  __builtin_amdgcn_sched_barrier(0);
  asm volatile("s_waitcnt vmcnt(6) lgkmcnt(0)" ::: "memory");  // B(c0) done
  __builtin_amdgcn_s_barrier();
  __builtin_amdgcn_sched_barrier(0);

  // --- main loop: 16 chunks of K=128 (4 steps each) ---
  for (int c = 0; c < NCH; ++c) {
    const unsigned char* rb = smem + BBASE + (c & 1) * BBUF;
    unsigned char* wbB = smem + BBASE + ((c + 1) & 1) * BBUF + bdst;
    const bool do_stage = (c + 1 < NCH);

    // chunk top: stage B(c+1) (4 gl_lds) -- lands during this chunk
    f4 q0[4], q1[4];  // !PRE only
    if (do_stage) {
      if constexpr (PRE) {
        #pragma unroll
        for (int j = 0; j < 4; ++j)
          __builtin_amdgcn_global_load_lds(
              (const unsigned int*)(WsrcB + wsrcb + (size_t)j * 16 * HD +
                                    (size_t)(c + 1) * 128),
              (unsigned int*)(wbB + j * 1024), 16, 0, 0);
      } else {
        #pragma unroll
        for (int j = 0; j < 4; ++j) {
          const size_t o = wsrcb + (size_t)j * 16 * HD + (size_t)(c + 1) * 128;
          q0[j] = *(const f4*)(Wf + o);
          q1[j] = *(const f4*)(Wf + o + 4);
        }
      }
    }
    __builtin_amdgcn_sched_barrier(0);

    #pragma unroll
    for (int st4 = 0; st4 < 4; ++st4) {
      const int t = c * 4 + st4;
      // Ledger (PRE, steady chunk): enter out=6(A)+4(B-top)=10.
      //  st4 0..2: vmcnt(8) retires the needed A-pair (oldest).
      //  st4  3 : needed A-pair sits behind B-top -> vmcnt(4) retires
      //           B(4)+A(2) (also proves B(c+1) for the boundary).
      // Last chunk: no B-top, out=6 -> vmcnt(4) every step.
      if constexpr (PRE) {
        if (st4 < 3 && c < NCH - 1) {
          asm volatile("s_waitcnt vmcnt(8)" ::: "memory");
        } else {
          asm volatile("s_waitcnt vmcnt(4)" ::: "memory");
        }
      } else {
        asm volatile("s_waitcnt vmcnt(0)" ::: "memory");
      }
      const unsigned char* slot = aring + (t & 3) * 2048;
      f4 v0 = *(const f4*)(slot + rdA0);
      f4 v1 = *(const f4*)(slot + rdA1);
      // issue A stage for t+3 (slot (t+3)&3 != t&3; clamp dups are benign
      // identical writes)
      const int tn = (t + 3 < 64) ? (t + 3) : 63;
      unsigned char* ad = aring + (tn & 3) * 2048 + lane * 16;
      __builtin_amdgcn_global_load_lds((const unsigned int*)(srcA0 + tn * 32),
                                       (unsigned int*)(ad), 16, 0, 0);
      __builtin_amdgcn_global_load_lds((const unsigned int*)(srcA1 + tn * 32),
                                       (unsigned int*)(ad + 1024), 16, 0, 0);
      __builtin_amdgcn_s_setprio(1);
      s8 ah, al;
      split8h(v0, v1, ah, al);
      #pragma unroll
      for (int f = 0; f < 4; ++f) {
        const unsigned char* bp = rb + st4 * 8192 + f * 1024 + lane * 16;
        s8 bh = *(const s8*)(bp);
        s8 bl = *(const s8*)(bp + 4096);
        acc[f] = mfma3(ah, al, bh, bl, acc[f]);
      }
      __builtin_amdgcn_s_setprio(0);
    }

    // !PRE: write staged B now (loads had 4 steps to land)
    if (do_stage) {
      if constexpr (!PRE) {
        #pragma unroll
        for (int j = 0; j < 4; ++j) {
          s8 th, tl;
          split8h(q0[j], q1[j], th, tl);
          *(s8*)(wbB + j * 1024) = bspl ? tl : th;
        }
      }
    }
    // boundary: B(c+1) already proven by st4=3's vmcnt(4); keep the
    // counted wait as a no-op guard + lgkm drain + barrier.
    if (do_stage) {
      __builtin_amdgcn_sched_barrier(0);
      if constexpr (PRE) {
        asm volatile("s_waitcnt vmcnt(8) lgkmcnt(0)" ::: "memory");
      } else {
        asm volatile("s_waitcnt lgkmcnt(0)" ::: "memory");
      }
      __builtin_amdgcn_s_barrier();
      __builtin_amdgcn_sched_barrier(0);
    }
  }

  // --- epilogue: lf region overlaps other waves' A rings -> barrier first ---
  __syncthreads();
  float* lf = (float*)smem + w * 1088;  // 16 tok x 68 floats
  #pragma unroll
  for (int f = 0; f < 4; ++f)
    #pragma unroll
    for (int r = 0; r < 4; ++r)
      lf[(kg * 4 + r) * 68 + f * 16 + ec] = acc[f][r];

  if (lane < 16) {
    float v[64];
    #pragma unroll
    for (int i = 0; i < 16; ++i) {
      f4 q = *(const f4*)(lf + lane * 68 + 4 * i);
      v[4 * i + 0] = q.x; v[4 * i + 1] = q.y;
      v[4 * i + 2] = q.z; v[4 * i + 3] = q.w;
    }
    epilogue64(v, out + (size_t)(tok0 + w * 16 + lane) * 6);
  }
}

extern "C" void kernel_launch(void* const* d_in, const int* in_sizes, int n_in,
                              void* d_out, int out_size, void* d_ws, size_t ws_size,
                              hipStream_t stream) {
  const float* X = (const float*)d_in[0];
  const float* Wf = (const float*)d_in[1];
  float* out = (float*)d_out;
  const int T = in_sizes[0] / HD;  // 32768
  const int nblk = T / 128;        // 256 blocks of 512 threads (8 waves)

  const size_t need = (size_t)NE * HD * sizeof(u16);  // 256 KB per split
  if (ws_size >= 2 * need) {
    u16* Whi = (u16*)d_ws;
    u16* Wlo = Whi + (size_t)NE * HD;
    cvtW2<<<dim3(256), dim3(64), 0, stream>>>(Wf, Whi, Wlo);
    gateF<true><<<dim3(nblk), dim3(512), 0, stream>>>(X, Wf, Whi, Wlo, out);
  } else {
    gateF<false><<<dim3(nblk), dim3(512), 0, stream>>>(X, Wf, nullptr, nullptr, out);
  }
}